// Round 22
// baseline (18.355 us; speedup 1.0000x reference)
//
#include <hip/hip_runtime.h>
#include <hip/hip_bf16.h>

typedef unsigned short ushort_t;
typedef unsigned int uint_t;
typedef __attribute__((ext_vector_type(8))) short short8;
typedef __attribute__((ext_vector_type(4))) float f32x4;

#define IN_DIM 256
#define OUT_DIM 256
#define BATCH 512
#define NSPL 11
#define KSLOT 12
#define KDIM (IN_DIM * KSLOT)    // 3072
#define BKU 384                  // ushorts per row per chunk (32 inputs x 12)

__device__ __forceinline__ uint_t pk2(float lo, float hi) {
  __hip_bfloat162 h = __float22bfloat162_rn(make_float2(lo, hi));  // v_cvt_pk_bf16_f32, RNE
  union { __hip_bfloat162 h2; uint_t u; } c; c.h2 = h;
  return c.u;
}

// ---- Kernel 1 (unchanged from R21 best): build A and W once; cells assembled
// in LDS, row image written out linearly coalesced. ----
__global__ __launch_bounds__(256) void build_aw(const float* __restrict__ x,
                                                const float* __restrict__ coef,
                                                const float* __restrict__ rw,
                                                const float* __restrict__ uw,
                                                ushort_t* __restrict__ A,
                                                ushort_t* __restrict__ W) {
  __shared__ float rowc[IN_DIM * NSPL];                    // 11.3 KB (W path)
  __shared__ __attribute__((aligned(8))) ushort_t stage[IN_DIM * KSLOT + 8];
  const int bx = blockIdx.x;
  const int t = threadIdx.x;

  if (bx < BATCH) {
    const float xf = x[bx * IN_DIM + t];
    const float tt = (xf + 1.75f) * 4.0f;
    const float fJ = floorf(tt);
    const int J = (int)fJ;
    const float u = tt - fJ;
    const float u2 = u * u, u3 = u2 * u, um = 1.0f - u;
    const float n0 = um * um * um * (1.0f / 6.0f);
    const float n1 = 0.5f * u3 - u2 + (4.0f / 6.0f);
    const float n2 = -0.5f * u3 + 0.5f * u2 + 0.5f * u + (1.0f / 6.0f);
    const float n3 = u3 * (1.0f / 6.0f);
    const float silu = xf / (1.0f + __expf(-xf));

    ushort_t* cb = &stage[t * KSLOT];
    ushort_t* dump = &stage[IN_DIM * KSLOT];
    *(unsigned long long*)&cb[0] = 0ull;
    *(unsigned long long*)&cb[4] = 0ull;
    *(unsigned long long*)&cb[8] = 0ull;

    const uint_t p01 = pk2(n0, n1);
    const uint_t p23 = pk2(n2, n3);
    const uint_t psl = pk2(silu, silu);
    const int base = J - 3;
    ushort_t* w0 = ((unsigned)(base + 0) <= 10u) ? (cb + base + 0) : (dump + 0);
    ushort_t* w1 = ((unsigned)(base + 1) <= 10u) ? (cb + base + 1) : (dump + 1);
    ushort_t* w2 = ((unsigned)(base + 2) <= 10u) ? (cb + base + 2) : (dump + 2);
    ushort_t* w3 = ((unsigned)(base + 3) <= 10u) ? (cb + base + 3) : (dump + 3);
    *w0 = (ushort_t)p01;
    *w1 = (ushort_t)(p01 >> 16);
    *w2 = (ushort_t)p23;
    *w3 = (ushort_t)(p23 >> 16);
    cb[11] = (ushort_t)psl;
    __syncthreads();

    uint_t* dst = (uint_t*)(A + (size_t)bx * KDIM);
    const uint_t* src = (const uint_t*)stage;
#pragma unroll
    for (int p = 0; p < 6; ++p) dst[t + p * 256] = src[t + p * 256];
  } else {
    const int o = bx - BATCH;
    const float* src = coef + (size_t)o * IN_DIM * NSPL;
#pragma unroll
    for (int j = 0; j < 11; ++j) rowc[t + j * 256] = src[t + j * 256];
    __syncthreads();

    const float us = uw[o * IN_DIM + t];
    const float r  = rw[o * IN_DIM + t];
    const float* c = &rowc[t * NSPL];
    uint_t* cell = (uint_t*)&stage[t * KSLOT];
    cell[0] = pk2(us * c[0], us * c[1]);
    cell[1] = pk2(us * c[2], us * c[3]);
    cell[2] = pk2(us * c[4], us * c[5]);
    cell[3] = pk2(us * c[6], us * c[7]);
    cell[4] = pk2(us * c[8], us * c[9]);
    cell[5] = pk2(us * c[10], r);
    __syncthreads();

    uint_t* dst = (uint_t*)(W + (size_t)o * KDIM);
    const uint_t* s2 = (const uint_t*)stage;
#pragma unroll
    for (int p = 0; p < 6; ++p) dst[t + p * 256] = s2[t + p * 256];
  }
}

// ---- Kernel 2: out = A · Wᵀ with WAVE SPECIALIZATION.
// Waves 0-1: pure compute (K split 2x192, 6 MFMA/phase, no global traffic).
// Wave 2: stages A (12 slabs), wave 3: stages W — depth-2 register staging so
// COMMIT is pure ds_write. Same barrier schedule for all waves. ----
__global__ __launch_bounds__(256, 3) void gemm(const ushort_t* __restrict__ A,
                                               const ushort_t* __restrict__ W,
                                               float* __restrict__ out) {
  __shared__ __attribute__((aligned(16))) ushort_t As[2][16 * BKU];   // 24.6 KB
  __shared__ __attribute__((aligned(16))) ushort_t Ws[2][16 * BKU];   // 24.6 KB
  __shared__ f32x4 red[64];

  const int tid = threadIdx.x;
  const int lane = tid & 63;
  const int w = tid >> 6;                          // 0,1 = compute; 2 = A-stager; 3 = W-stager
  const int B = blockIdx.x;
  const int mt = B >> 4;
  const int nt = ((B & 7) << 1) | ((B >> 3) & 1);  // XCD-aware (bijective, 512%8==0)
  const int b0 = mt * 16, o0 = nt * 16;
  const int mn = lane & 15;
  const int klane = (lane >> 4) * 8;

  const int mrow = mn * BKU;
  const int msw = (mn & 7) << 3;

  // stager geometry: 12 slabs x 512 ushorts = full 16x384 tile of ONE matrix
  int srcOff[12], ldsOff[12];
  const ushort_t* SP = nullptr;
  ushort_t* L0 = nullptr;
  ushort_t* L1 = nullptr;
  if (w >= 2) {
#pragma unroll
    for (int i = 0; i < 12; ++i) {
      const int F = (i * 64 + lane) * 8;
      const int rowi = F / BKU;                    // 0..15
      const int coli = F % BKU;
      srcOff[i] = rowi * KDIM + coli;              // global: linear, coalesced
      ldsOff[i] = rowi * BKU + (coli ^ ((rowi & 7) << 3));   // T2 swizzle
    }
    SP = (w == 2) ? (A + (size_t)b0 * KDIM) : (W + (size_t)o0 * KDIM);
    L0 = (w == 2) ? &As[0][0] : &Ws[0][0];
    L1 = (w == 2) ? &As[1][0] : &Ws[1][0];
  }

  f32x4 acc = {0.f, 0.f, 0.f, 0.f};

  // depth-2 staging registers (stager waves only; rule #20: all static names)
  short8 g0, g1, g2, g3, g4, g5, g6, g7, g8, g9, g10, g11;   // stage 0 (even chunks)
  short8 h0, h1, h2, h3, h4, h5, h6, h7, h8, h9, h10, h11;   // stage 1 (odd chunks)

#define ISSUE_G(C) { const int kb = (C) * BKU;                                \
    g0  = *(const short8*)(SP + srcOff[0]  + kb);                             \
    g1  = *(const short8*)(SP + srcOff[1]  + kb);                             \
    g2  = *(const short8*)(SP + srcOff[2]  + kb);                             \
    g3  = *(const short8*)(SP + srcOff[3]  + kb);                             \
    g4  = *(const short8*)(SP + srcOff[4]  + kb);                             \
    g5  = *(const short8*)(SP + srcOff[5]  + kb);                             \
    g6  = *(const short8*)(SP + srcOff[6]  + kb);                             \
    g7  = *(const short8*)(SP + srcOff[7]  + kb);                             \
    g8  = *(const short8*)(SP + srcOff[8]  + kb);                             \
    g9  = *(const short8*)(SP + srcOff[9]  + kb);                             \
    g10 = *(const short8*)(SP + srcOff[10] + kb);                             \
    g11 = *(const short8*)(SP + srcOff[11] + kb); }
#define ISSUE_H(C) { const int kb = (C) * BKU;                                \
    h0  = *(const short8*)(SP + srcOff[0]  + kb);                             \
    h1  = *(const short8*)(SP + srcOff[1]  + kb);                             \
    h2  = *(const short8*)(SP + srcOff[2]  + kb);                             \
    h3  = *(const short8*)(SP + srcOff[3]  + kb);                             \
    h4  = *(const short8*)(SP + srcOff[4]  + kb);                             \
    h5  = *(const short8*)(SP + srcOff[5]  + kb);                             \
    h6  = *(const short8*)(SP + srcOff[6]  + kb);                             \
    h7  = *(const short8*)(SP + srcOff[7]  + kb);                             \
    h8  = *(const short8*)(SP + srcOff[8]  + kb);                             \
    h9  = *(const short8*)(SP + srcOff[9]  + kb);                             \
    h10 = *(const short8*)(SP + srcOff[10] + kb);                             \
    h11 = *(const short8*)(SP + srcOff[11] + kb); }
#define COMMIT_G(LP) {                                                        \
    *(short8*)&LP[ldsOff[0]]  = g0;  *(short8*)&LP[ldsOff[1]]  = g1;          \
    *(short8*)&LP[ldsOff[2]]  = g2;  *(short8*)&LP[ldsOff[3]]  = g3;          \
    *(short8*)&LP[ldsOff[4]]  = g4;  *(short8*)&LP[ldsOff[5]]  = g5;          \
    *(short8*)&LP[ldsOff[6]]  = g6;  *(short8*)&LP[ldsOff[7]]  = g7;          \
    *(short8*)&LP[ldsOff[8]]  = g8;  *(short8*)&LP[ldsOff[9]]  = g9;          \
    *(short8*)&LP[ldsOff[10]] = g10; *(short8*)&LP[ldsOff[11]] = g11; }
#define COMMIT_H(LP) {                                                        \
    *(short8*)&LP[ldsOff[0]]  = h0;  *(short8*)&LP[ldsOff[1]]  = h1;          \
    *(short8*)&LP[ldsOff[2]]  = h2;  *(short8*)&LP[ldsOff[3]]  = h3;          \
    *(short8*)&LP[ldsOff[4]]  = h4;  *(short8*)&LP[ldsOff[5]]  = h5;          \
    *(short8*)&LP[ldsOff[6]]  = h6;  *(short8*)&LP[ldsOff[7]]  = h7;          \
    *(short8*)&LP[ldsOff[8]]  = h8;  *(short8*)&LP[ldsOff[9]]  = h9;          \
    *(short8*)&LP[ldsOff[10]] = h10; *(short8*)&LP[ldsOff[11]] = h11; }

  // compute waves: 6 MFMA per phase, K-slice = [w*192, w*192+192)
#define MFMA6(BUF) { _Pragma("unroll")                                        \
    for (int q = 0; q < 6; ++q) {                                             \
      const int kidx = w * 192 + q * 32 + klane;                              \
      const int idx = mrow + (kidx ^ msw);                                    \
      short8 af  = *(const short8*)&As[BUF][idx];                             \
      short8 bfr = *(const short8*)&Ws[BUF][idx];                             \
      acc = __builtin_amdgcn_mfma_f32_16x16x32_bf16(af, bfr, acc, 0, 0, 0); }}

  // prologue: stagers put chunk 0 in LDS (one-time vmcnt stall) and chunk 1 in flight
  if (w >= 2) {
    ISSUE_G(0)
    COMMIT_G(L0)
    ISSUE_H(1)
  }
  __syncthreads();

  // 8 phases; chunk c in buf c&1; stage G = even chunks, H = odd chunks
#pragma unroll
  for (int cc = 0; cc < 4; ++cc) {
    // even phase 2cc: compute buf0; stagers issue chunk 2cc+2, commit chunk 2cc+1
    if (w >= 2) {
      if (cc < 3) { ISSUE_G(2 * cc + 2) }
      COMMIT_H(L1)
    } else {
      MFMA6(0)
    }
    __syncthreads();

    // odd phase 2cc+1: compute buf1; stagers issue chunk 2cc+3, commit chunk 2cc+2
    if (w >= 2) {
      if (cc < 3) {
        ISSUE_H(2 * cc + 3)
        COMMIT_G(L0)
      }
    } else {
      MFMA6(1)
    }
    if (cc < 3) __syncthreads();
  }

  // reduce: wave1 partial -> wave0 adds and writes (stagers idle)
  if (w == 1) red[lane] = acc;
  __syncthreads();

  if (w == 0) {
    const f32x4 t1 = red[lane];
#pragma unroll
    for (int q = 0; q < 4; ++q) acc[q] += t1[q];

    // C/D layout (HW-verified): col = lane&15, row = (lane>>4)*4 + reg
    const int col = o0 + mn;
    const int rbase = b0 + (lane >> 4) * 4;
#pragma unroll
    for (int r = 0; r < 4; ++r) {
      out[(size_t)(rbase + r) * OUT_DIM + col] = acc[r];
    }
  }
}

extern "C" void kernel_launch(void* const* d_in, const int* in_sizes, int n_in,
                              void* d_out, int out_size, void* d_ws, size_t ws_size,
                              hipStream_t stream) {
  const float* x    = (const float*)d_in[0];
  const float* coef = (const float*)d_in[1];
  const float* rw   = (const float*)d_in[2];
  const float* uw   = (const float*)d_in[3];
  float* out = (float*)d_out;

  ushort_t* A = (ushort_t*)d_ws;                             // 512*3072*2 = 3.0 MB
  ushort_t* W = A + (size_t)BATCH * KDIM;                    // 256*3072*2 = 1.5 MB

  build_aw<<<BATCH + OUT_DIM, 256, 0, stream>>>(x, coef, rw, uw, A, W);
  gemm<<<512, 256, 0, stream>>>(A, W, out);
}